// Round 1
// baseline (10240.725 us; speedup 1.0000x reference)
//
#include <hip/hip_runtime.h>
#include <hip/hip_bf16.h>

#define H100 100

// ---------------- degree / normalization ----------------
__global__ __launch_bounds__(256) void fill1_kernel(float* __restrict__ d, int n) {
    int t = blockIdx.x * 256 + threadIdx.x;
    if (t < n) d[t] = 1.0f;   // self-loop contributes 1 to deg
}

__global__ __launch_bounds__(256) void deg_edge_kernel(const int* __restrict__ col,
                                                       float* __restrict__ deg, int E) {
    int t = blockIdx.x * 256 + threadIdx.x;
    if (t < E) unsafeAtomicAdd(&deg[col[t]], 1.0f);
}

__global__ __launch_bounds__(256) void rsqrt_kernel(float* __restrict__ d, int n) {
    int t = blockIdx.x * 256 + threadIdx.x;
    if (t < n) d[t] = rsqrtf(d[t]);   // deg >= 1 always (self-loops)
}

// ---------------- GEMM: xw[i][j] = (h[i] @ W)[j] * dis[i] ----------------
// Tile: 64 nodes x 100 channels per block of 256 threads.
// thread (tx 0..15, ty 0..15): 4 nodes (ty*4..) x 8 channels (tx*4.., 64+tx*4..)
// W staged in LDS in two K-halves to stay under the 64KB static-LDS limit.
template <int CIN>
__global__ __launch_bounds__(256) void gemm_scale_kernel(
    const float* __restrict__ hin, const float* __restrict__ W,
    const float* __restrict__ dis, float* __restrict__ xw, int n)
{
    constexpr int KH = (CIN + 1) / 2;
    __shared__ float Wl[KH * H100 + 32];   // +32: harmless OOB reads for tx>=9 2nd group
    __shared__ float hsT[CIN * 68];        // transposed tile, padded stride 68
    const int tid = threadIdx.x;
    const int node0 = blockIdx.x * 64;

    // stage h tile transposed (global reads fully coalesced)
    for (int idx = tid; idx < 64 * CIN; idx += 256) {
        int r = idx / CIN;
        int k = idx - r * CIN;
        int node = node0 + r;
        hsT[k * 68 + r] = (node < n) ? hin[node * CIN + k] : 0.0f;
    }

    const int tx = tid & 15;
    const int ty = tid >> 4;
    float acc0[4][4] = {{0.f}};
    float acc1[4][4] = {{0.f}};

    for (int p = 0; p < 2; ++p) {
        const int k0 = p * KH;
        const int kn = (CIN - k0 < KH) ? (CIN - k0) : KH;
        __syncthreads();  // hsT ready (p=0) / previous-phase readers done (p=1)
        for (int idx = tid; idx < kn * H100; idx += 256)
            Wl[idx] = W[k0 * H100 + idx];
        __syncthreads();
        for (int kk = 0; kk < kn; ++kk) {
            const float4 a  = *reinterpret_cast<const float4*>(&hsT[(k0 + kk) * 68 + ty * 4]);
            const float4 w0 = *reinterpret_cast<const float4*>(&Wl[kk * H100 + tx * 4]);
            const float4 w1 = *reinterpret_cast<const float4*>(&Wl[kk * H100 + 64 + tx * 4]);
            const float av[4]  = {a.x, a.y, a.z, a.w};
            const float w0v[4] = {w0.x, w0.y, w0.z, w0.w};
            const float w1v[4] = {w1.x, w1.y, w1.z, w1.w};
            #pragma unroll
            for (int ni = 0; ni < 4; ++ni) {
                #pragma unroll
                for (int ci = 0; ci < 4; ++ci) {
                    acc0[ni][ci] += av[ni] * w0v[ci];
                    acc1[ni][ci] += av[ni] * w1v[ci];
                }
            }
        }
    }

    #pragma unroll
    for (int ni = 0; ni < 4; ++ni) {
        const int node = node0 + ty * 4 + ni;
        if (node >= n) continue;
        const float s = dis[node];
        float4 o0 = make_float4(acc0[ni][0] * s, acc0[ni][1] * s, acc0[ni][2] * s, acc0[ni][3] * s);
        *reinterpret_cast<float4*>(&xw[node * H100 + tx * 4]) = o0;
        if (tx < 9) {  // channels 64..99
            float4 o1 = make_float4(acc1[ni][0] * s, acc1[ni][1] * s, acc1[ni][2] * s, acc1[ni][3] * s);
            *reinterpret_cast<float4*>(&xw[node * H100 + 64 + tx * 4]) = o1;
        }
    }
}

// ---------------- edge scatter: agg[col] += xw[row] ----------------
// 25 threads per edge, one float4 each (100 channels).
__global__ __launch_bounds__(256) void scatter_kernel(
    const int* __restrict__ row, const int* __restrict__ col,
    const float* __restrict__ xw, float* __restrict__ agg, int E)
{
    const unsigned tid = blockIdx.x * 256u + threadIdx.x;
    const unsigned e = tid / 25u;
    const unsigned q = tid - e * 25u;
    if (e >= (unsigned)E) return;
    const int r = row[e];
    const int c = col[e];
    const float4 v = *reinterpret_cast<const float4*>(&xw[r * H100 + q * 4]);
    float* dst = &agg[c * H100 + q * 4];
    unsafeAtomicAdd(dst + 0, v.x);
    unsafeAtomicAdd(dst + 1, v.y);
    unsafeAtomicAdd(dst + 2, v.z);
    unsafeAtomicAdd(dst + 3, v.w);
}

// ---------------- epilogue: self-loop + dis scale + bias + BN (+ReLU) ----------------
__global__ __launch_bounds__(256) void epilogue_relu_kernel(
    const float* __restrict__ agg, const float* __restrict__ xw,
    const float* __restrict__ dis, const float* __restrict__ b,
    const float* __restrict__ gamma, const float* __restrict__ beta,
    const float* __restrict__ mean, const float* __restrict__ var,
    float* __restrict__ hout, int n)
{
    int t = blockIdx.x * 256 + threadIdx.x;
    if (t >= n * H100) return;
    int i = t / H100;
    int j = t - i * H100;
    float s  = gamma[j] * rsqrtf(var[j] + 1e-5f);
    float tt = (b[j] - mean[j]) * s + beta[j];
    float v  = dis[i] * (agg[t] + xw[t]);
    float hv = v * s + tt;
    hout[t] = hv > 0.0f ? hv : 0.0f;
}

__global__ __launch_bounds__(256) void epilogue_pool_kernel(
    const float* __restrict__ agg, const float* __restrict__ xw,
    const float* __restrict__ dis, const float* __restrict__ b,
    const float* __restrict__ gamma, const float* __restrict__ beta,
    const float* __restrict__ mean, const float* __restrict__ var,
    const int* __restrict__ batch, float* __restrict__ g, int n)
{
    int t = blockIdx.x * 256 + threadIdx.x;
    if (t >= n * H100) return;
    int i = t / H100;
    int j = t - i * H100;
    float s  = gamma[j] * rsqrtf(var[j] + 1e-5f);
    float tt = (b[j] - mean[j]) * s + beta[j];
    float v  = dis[i] * (agg[t] + xw[t]);
    float hv = v * s + tt;   // no ReLU on last layer
    unsafeAtomicAdd(&g[batch[i] * H100 + j], hv);
}

// ---------------- head: out = leakyrelu(g @ head_W + head_b, 0.1) ----------------
__global__ __launch_bounds__(64) void head_kernel(
    const float* __restrict__ g, const float* __restrict__ hW,
    const float* __restrict__ hb, float* __restrict__ out, int G)
{
    int gi = blockIdx.x;
    int lane = threadIdx.x;
    float acc = 0.f;
    for (int j = lane; j < H100; j += 64) acc += g[gi * H100 + j] * hW[j];
    #pragma unroll
    for (int off = 32; off > 0; off >>= 1) acc += __shfl_down(acc, off);
    if (lane == 0) {
        float o = acc + hb[0];
        out[gi] = (o >= 0.f) ? o : 0.1f * o;
    }
}

extern "C" void kernel_launch(void* const* d_in, const int* in_sizes, int n_in,
                              void* d_out, int out_size, void* d_ws, size_t ws_size,
                              hipStream_t stream) {
    const float* x       = (const float*)d_in[0];
    const int*   ei      = (const int*)d_in[1];
    const int*   batch   = (const int*)d_in[2];
    const float* W0      = (const float*)d_in[3];
    const float* Ws      = (const float*)d_in[4];
    const float* biases  = (const float*)d_in[5];
    const float* gamma   = (const float*)d_in[6];
    const float* beta    = (const float*)d_in[7];
    const float* bn_mean = (const float*)d_in[8];
    const float* bn_var  = (const float*)d_in[9];
    const float* headW   = (const float*)d_in[10];
    const float* headb   = (const float*)d_in[11];
    float* out = (float*)d_out;

    const int N = in_sizes[2];        // 100000 nodes
    const int E = in_sizes[1] / 2;    // 1600000 edges
    const int G = out_size;           // 2048 graphs (NUM_TASKS==1)
    const int* row  = ei;
    const int* colp = ei + E;

    // workspace carve-up (256B-aligned)
    char* ws = (char*)d_ws;
    size_t off = 0;
    auto carve = [&](size_t bytes) -> float* {
        float* p = (float*)(ws + off);
        off += (bytes + 255) & ~(size_t)255;
        return p;
    };
    float* dis  = carve((size_t)N * 4);
    float* xw   = carve((size_t)N * H100 * 4);
    float* agg  = carve((size_t)N * H100 * 4);
    float* hbuf = carve((size_t)N * H100 * 4);
    float* g    = carve((size_t)G * H100 * 4);

    const int nb_n  = (N + 255) / 256;
    const int nb_e  = (E + 255) / 256;
    const int nb_nh = (N * H100 + 255) / 256;
    const int nb_sc = (int)(((size_t)E * 25 + 255) / 256);
    const int nb_g  = (N + 63) / 64;

    // normalization: dis = rsqrt(1 + in_degree)
    fill1_kernel<<<nb_n, 256, 0, stream>>>(dis, N);
    deg_edge_kernel<<<nb_e, 256, 0, stream>>>(colp, dis, E);
    rsqrt_kernel<<<nb_n, 256, 0, stream>>>(dis, N);

    for (int l = 0; l < 4; ++l) {
        hipMemsetAsync(agg, 0, (size_t)N * H100 * 4, stream);
        if (l == 0)
            gemm_scale_kernel<33><<<nb_g, 256, 0, stream>>>(x, W0, dis, xw, N);
        else
            gemm_scale_kernel<H100><<<nb_g, 256, 0, stream>>>(hbuf, Ws + (size_t)(l - 1) * H100 * H100,
                                                              dis, xw, N);
        scatter_kernel<<<nb_sc, 256, 0, stream>>>(row, colp, xw, agg, E);
        if (l < 3) {
            epilogue_relu_kernel<<<nb_nh, 256, 0, stream>>>(
                agg, xw, dis, biases + l * H100, gamma + l * H100, beta + l * H100,
                bn_mean + l * H100, bn_var + l * H100, hbuf, N);
        } else {
            hipMemsetAsync(g, 0, (size_t)G * H100 * 4, stream);
            epilogue_pool_kernel<<<nb_nh, 256, 0, stream>>>(
                agg, xw, dis, biases + l * H100, gamma + l * H100, beta + l * H100,
                bn_mean + l * H100, bn_var + l * H100, batch, g, N);
        }
    }
    head_kernel<<<G, 64, 0, stream>>>(g, headW, headb, out, G);
}

// Round 2
// 1009.331 us; speedup vs baseline: 10.1461x; 10.1461x over previous
//
#include <hip/hip_runtime.h>
#include <hip/hip_bf16.h>

#define H100 100
#define BN_EPS 1e-5f

// ================= CSR build =================
__global__ __launch_bounds__(256) void deg_int_kernel(const int* __restrict__ col,
                                                      int* __restrict__ degi, int E) {
    int t = blockIdx.x * 256 + threadIdx.x;
    if (t < E) atomicAdd(&degi[col[t]], 1);
}

// per-block inclusive scan of degi -> rowptr[gid+1]; block total -> bsum[b]
__global__ __launch_bounds__(256) void scan1_kernel(const int* __restrict__ degi,
                                                    int* __restrict__ rowptr,
                                                    int* __restrict__ bsum, int n) {
    __shared__ int lds[256];
    const int t = threadIdx.x;
    const int gid = blockIdx.x * 256 + t;
    int v = (gid < n) ? degi[gid] : 0;
    lds[t] = v;
    __syncthreads();
    for (int off = 1; off < 256; off <<= 1) {
        int u = (t >= off) ? lds[t - off] : 0;
        __syncthreads();
        lds[t] += u;
        __syncthreads();
    }
    if (gid < n) rowptr[gid + 1] = lds[t];
    if (t == 255) bsum[blockIdx.x] = lds[t];
}

// single-block exclusive scan of bsum (nb <= 1024)
__global__ __launch_bounds__(1024) void scan2_kernel(int* __restrict__ bsum, int nb) {
    __shared__ int lds[1024];
    const int t = threadIdx.x;
    int v = (t < nb) ? bsum[t] : 0;
    lds[t] = v;
    __syncthreads();
    for (int off = 1; off < 1024; off <<= 1) {
        int u = (t >= off) ? lds[t - off] : 0;
        __syncthreads();
        lds[t] += u;
        __syncthreads();
    }
    if (t < nb) bsum[t] = lds[t] - v;   // exclusive
}

// finalize rowptr; derive dis = rsqrt(deg+1) and cursor = rowptr[i]
__global__ __launch_bounds__(256) void scan3_kernel(int* __restrict__ rowptr,
                                                    const int* __restrict__ bsum,
                                                    const int* __restrict__ degi,
                                                    float* __restrict__ dis,
                                                    int* __restrict__ cursor, int n) {
    const int gid = blockIdx.x * 256 + threadIdx.x;
    if (gid >= n) return;
    const int d = degi[gid];
    const int rp1 = rowptr[gid + 1] + bsum[blockIdx.x];
    rowptr[gid + 1] = rp1;
    cursor[gid] = rp1 - d;              // == rowptr[gid]
    if (gid == 0) rowptr[0] = 0;
    dis[gid] = rsqrtf((float)(d + 1));  // +1 self-loop
}

__global__ __launch_bounds__(256) void fill_csr_kernel(const int* __restrict__ row,
                                                       const int* __restrict__ col,
                                                       int* __restrict__ cursor,
                                                       int* __restrict__ srcidx, int E) {
    int e = blockIdx.x * 256 + threadIdx.x;
    if (e >= E) return;
    int slot = atomicAdd(&cursor[col[e]], 1);
    srcidx[slot] = row[e];
}

// ================= BN fold: s = gamma*rsqrt(var+eps), t = (b-mean)*s+beta =================
__global__ __launch_bounds__(256) void bnprep_kernel(const float* __restrict__ b,
                                                     const float* __restrict__ gamma,
                                                     const float* __restrict__ beta,
                                                     const float* __restrict__ mean,
                                                     const float* __restrict__ var,
                                                     float* __restrict__ sarr,
                                                     float* __restrict__ tarr) {
    int idx = blockIdx.x * 256 + threadIdx.x;
    if (idx >= 4 * H100) return;
    float s = gamma[idx] * rsqrtf(var[idx] + BN_EPS);
    sarr[idx] = s;
    tarr[idx] = (b[idx] - mean[idx]) * s + beta[idx];
}

// ================= GEMM: xw[i][j] = (h[i] @ W)[j] * dis[i] =================
template <int CIN>
__global__ __launch_bounds__(256) void gemm_scale_kernel(
    const float* __restrict__ hin, const float* __restrict__ W,
    const float* __restrict__ dis, float* __restrict__ xw, int n)
{
    constexpr int KH = (CIN + 1) / 2;
    __shared__ float Wl[KH * H100 + 32];
    __shared__ float hsT[CIN * 68];
    const int tid = threadIdx.x;
    const int node0 = blockIdx.x * 64;

    for (int idx = tid; idx < 64 * CIN; idx += 256) {
        int r = idx / CIN;
        int k = idx - r * CIN;
        int node = node0 + r;
        hsT[k * 68 + r] = (node < n) ? hin[node * CIN + k] : 0.0f;
    }

    const int tx = tid & 15;
    const int ty = tid >> 4;
    float acc0[4][4] = {{0.f}};
    float acc1[4][4] = {{0.f}};

    for (int p = 0; p < 2; ++p) {
        const int k0 = p * KH;
        const int kn = (CIN - k0 < KH) ? (CIN - k0) : KH;
        __syncthreads();
        for (int idx = tid; idx < kn * H100; idx += 256)
            Wl[idx] = W[k0 * H100 + idx];
        __syncthreads();
        for (int kk = 0; kk < kn; ++kk) {
            const float4 a  = *reinterpret_cast<const float4*>(&hsT[(k0 + kk) * 68 + ty * 4]);
            const float4 w0 = *reinterpret_cast<const float4*>(&Wl[kk * H100 + tx * 4]);
            const float4 w1 = *reinterpret_cast<const float4*>(&Wl[kk * H100 + 64 + tx * 4]);
            const float av[4]  = {a.x, a.y, a.z, a.w};
            const float w0v[4] = {w0.x, w0.y, w0.z, w0.w};
            const float w1v[4] = {w1.x, w1.y, w1.z, w1.w};
            #pragma unroll
            for (int ni = 0; ni < 4; ++ni)
                #pragma unroll
                for (int ci = 0; ci < 4; ++ci) {
                    acc0[ni][ci] += av[ni] * w0v[ci];
                    acc1[ni][ci] += av[ni] * w1v[ci];
                }
        }
    }

    #pragma unroll
    for (int ni = 0; ni < 4; ++ni) {
        const int node = node0 + ty * 4 + ni;
        if (node >= n) continue;
        const float s = dis[node];
        float4 o0 = make_float4(acc0[ni][0] * s, acc0[ni][1] * s, acc0[ni][2] * s, acc0[ni][3] * s);
        *reinterpret_cast<float4*>(&xw[node * H100 + tx * 4]) = o0;
        if (tx < 9) {
            float4 o1 = make_float4(acc1[ni][0] * s, acc1[ni][1] * s, acc1[ni][2] * s, acc1[ni][3] * s);
            *reinterpret_cast<float4*>(&xw[node * H100 + 64 + tx * 4]) = o1;
        }
    }
}

// ================= gather + fused epilogue =================
// 25 threads per dest node, one float4 of channels each.
template <bool RELU>
__global__ __launch_bounds__(256) void gather_kernel(
    const int* __restrict__ rowptr, const int* __restrict__ srcidx,
    const float* __restrict__ xw, const float* __restrict__ dis,
    const float* __restrict__ sarr, const float* __restrict__ tarr,
    float* __restrict__ hout, int n)
{
    const int t = blockIdx.x * 256 + threadIdx.x;
    const int node = t / 25;
    if (node >= n) return;
    const int q = t - node * 25;
    const float4* __restrict__ xwv = reinterpret_cast<const float4*>(xw);

    float4 acc = xwv[node * 25 + q];          // self-loop term (already *dis[node])
    const int i1 = rowptr[node + 1];
    int i = rowptr[node];
    for (; i + 1 < i1; i += 2) {
        const int s0 = srcidx[i];
        const int s1 = srcidx[i + 1];
        const float4 v0 = xwv[s0 * 25 + q];
        const float4 v1 = xwv[s1 * 25 + q];
        acc.x += v0.x + v1.x;
        acc.y += v0.y + v1.y;
        acc.z += v0.z + v1.z;
        acc.w += v0.w + v1.w;
    }
    if (i < i1) {
        const float4 v0 = xwv[srcidx[i] * 25 + q];
        acc.x += v0.x; acc.y += v0.y; acc.z += v0.z; acc.w += v0.w;
    }

    const float dn = dis[node];
    const int j = q * 4;
    const float4 s  = *reinterpret_cast<const float4*>(&sarr[j]);
    const float4 tt = *reinterpret_cast<const float4*>(&tarr[j]);
    float4 hv;
    hv.x = acc.x * dn * s.x + tt.x;
    hv.y = acc.y * dn * s.y + tt.y;
    hv.z = acc.z * dn * s.z + tt.z;
    hv.w = acc.w * dn * s.w + tt.w;
    if (RELU) {
        hv.x = fmaxf(hv.x, 0.f); hv.y = fmaxf(hv.y, 0.f);
        hv.z = fmaxf(hv.z, 0.f); hv.w = fmaxf(hv.w, 0.f);
    }
    reinterpret_cast<float4*>(hout)[node * 25 + q] = hv;
}

// ================= fused global_add_pool + head + LeakyReLU =================
// one block per graph; batch is sorted -> binary-search the node range.
__global__ __launch_bounds__(128) void pool_head_kernel(
    const float* __restrict__ h, const int* __restrict__ batch,
    const float* __restrict__ hW, const float* __restrict__ hb,
    float* __restrict__ out, int n)
{
    const int gi = blockIdx.x;
    int lo = 0, hi = n;
    while (lo < hi) { int mid = (lo + hi) >> 1; if (batch[mid] < gi) lo = mid + 1; else hi = mid; }
    const int start = lo;
    hi = n;
    while (lo < hi) { int mid = (lo + hi) >> 1; if (batch[mid] < gi + 1) lo = mid + 1; else hi = mid; }
    const int end = lo;

    const int j = threadIdx.x;
    float acc = 0.f;
    if (j < H100) {
        for (int i = start; i < end; ++i) acc += h[i * H100 + j];
        acc *= hW[j];
    }
    __shared__ float lds[128];
    lds[j] = acc;
    __syncthreads();
    for (int off = 64; off > 0; off >>= 1) {
        if (j < off) lds[j] += lds[j + off];
        __syncthreads();
    }
    if (j == 0) {
        float o = lds[0] + hb[0];
        out[gi] = (o >= 0.f) ? o : 0.1f * o;
    }
}

extern "C" void kernel_launch(void* const* d_in, const int* in_sizes, int n_in,
                              void* d_out, int out_size, void* d_ws, size_t ws_size,
                              hipStream_t stream) {
    const float* x       = (const float*)d_in[0];
    const int*   ei      = (const int*)d_in[1];
    const int*   batch   = (const int*)d_in[2];
    const float* W0      = (const float*)d_in[3];
    const float* Ws      = (const float*)d_in[4];
    const float* biases  = (const float*)d_in[5];
    const float* gamma   = (const float*)d_in[6];
    const float* beta    = (const float*)d_in[7];
    const float* bn_mean = (const float*)d_in[8];
    const float* bn_var  = (const float*)d_in[9];
    const float* headW   = (const float*)d_in[10];
    const float* headb   = (const float*)d_in[11];
    float* out = (float*)d_out;

    const int N = in_sizes[2];
    const int E = in_sizes[1] / 2;
    const int G = out_size;
    const int* row  = ei;
    const int* colp = ei + E;

    char* ws = (char*)d_ws;
    size_t off = 0;
    auto carve = [&](size_t bytes) -> void* {
        void* p = (void*)(ws + off);
        off += (bytes + 255) & ~(size_t)255;
        return p;
    };
    float* dis    = (float*)carve((size_t)N * 4);
    float* xw     = (float*)carve((size_t)N * H100 * 4);
    float* hbuf   = (float*)carve((size_t)N * H100 * 4);
    int*   degi   = (int*)carve((size_t)N * 4);
    int*   rowptr = (int*)carve((size_t)(N + 1) * 4);
    int*   cursor = (int*)carve((size_t)N * 4);
    int*   srcidx = (int*)carve((size_t)E * 4);
    int*   bsum   = (int*)carve(1024 * 4);
    float* sarr   = (float*)carve(4 * H100 * 4);
    float* tarr   = (float*)carve(4 * H100 * 4);

    const int nb_n  = (N + 255) / 256;
    const int nb_e  = (E + 255) / 256;
    const int nb_g  = (N + 63) / 64;
    const int nb_ga = (N * 25 + 255) / 256;

    // ---- CSR build (once per call) ----
    hipMemsetAsync(degi, 0, (size_t)N * 4, stream);
    deg_int_kernel<<<nb_e, 256, 0, stream>>>(colp, degi, E);
    scan1_kernel<<<nb_n, 256, 0, stream>>>(degi, rowptr, bsum, N);
    scan2_kernel<<<1, 1024, 0, stream>>>(bsum, nb_n);
    scan3_kernel<<<nb_n, 256, 0, stream>>>(rowptr, bsum, degi, dis, cursor, N);
    fill_csr_kernel<<<nb_e, 256, 0, stream>>>(row, colp, cursor, srcidx, E);
    bnprep_kernel<<<2, 256, 0, stream>>>(biases, gamma, beta, bn_mean, bn_var, sarr, tarr);

    // ---- 4 GCN layers ----
    for (int l = 0; l < 4; ++l) {
        if (l == 0)
            gemm_scale_kernel<33><<<nb_g, 256, 0, stream>>>(x, W0, dis, xw, N);
        else
            gemm_scale_kernel<H100><<<nb_g, 256, 0, stream>>>(hbuf, Ws + (size_t)(l - 1) * H100 * H100,
                                                              dis, xw, N);
        if (l < 3)
            gather_kernel<true><<<nb_ga, 256, 0, stream>>>(rowptr, srcidx, xw, dis,
                                                           sarr + l * H100, tarr + l * H100, hbuf, N);
        else
            gather_kernel<false><<<nb_ga, 256, 0, stream>>>(rowptr, srcidx, xw, dis,
                                                            sarr + l * H100, tarr + l * H100, hbuf, N);
    }

    // ---- pool + head ----
    pool_head_kernel<<<G, 128, 0, stream>>>(hbuf, batch, headW, headb, out, N);
}